// Round 1
// baseline (272.522 us; speedup 1.0000x reference)
//
#include <hip/hip_runtime.h>
#include <math.h>

#define EN 16

// mono(x) = exp(-(x*w1 + b1)) . w2 + b2  — fast native exp.
// Gate-safety: angle gates depend only on force *direction*, never on mono
// magnitudes, so __expf's ~1ulp deviation cannot flip a gate.
__device__ __forceinline__ float mono_fast(float x,
    const float* __restrict__ w1, const float* __restrict__ b1,
    const float* __restrict__ w2, const float* __restrict__ b2) {
    float acc = 0.0f;
#pragma unroll
    for (int e = 0; e < EN; ++e) {
        float pre = fmaf(x, w1[e], b1[e]);
        acc = fmaf(__expf(-pre), w2[e], acc);
    }
    return acc + b2[0];
}

// One thread per agent; all K=8 neighbors handled in-lane.
// vs the previous 8-lane/agent version: no shuffles/ballots, ego row loaded
// once (not 8x), dest force computed once (not 8x), border monos 2/agent
// (not 8). Per-(n,k) arithmetic is bit-identical; the neighbor reduction
// reproduces the old xor-butterfly association ((0+1)+(2+3))+((4+5)+(6+7)).
extern "C" __global__ void __launch_bounds__(256)
sfm_kernel(const float* __restrict__ ego, const float* __restrict__ nei,
           const float* __restrict__ border, const float* __restrict__ rec,
           const float* __restrict__ p_dest, const float* __restrict__ angle,
           const float* __restrict__ rep_w1, const float* __restrict__ rep_b1,
           const float* __restrict__ rep_w2, const float* __restrict__ rep_b2,
           const float* __restrict__ att_w1, const float* __restrict__ att_b1,
           const float* __restrict__ att_w2, const float* __restrict__ att_b2,
           const float* __restrict__ bor_w1, const float* __restrict__ bor_b1,
           const float* __restrict__ bor_w2, const float* __restrict__ bor_b2,
           const float* __restrict__ del_w1, const float* __restrict__ del_b1,
           const float* __restrict__ del_w2, const float* __restrict__ del_b2,
           float* __restrict__ out, int N)
{
    const int n = blockIdx.x * blockDim.x + threadIdx.x;
    if (n >= N) return;

    const float ang = angle[0];
    const float p0 = p_dest[0], p1 = p_dest[1];

    // ego row (64B, loaded once per agent)
    const float* er = ego + (size_t)n * 16;
    float4 ea = *(const float4*)(er);       // cols 0..3
    float4 eb = *(const float4*)(er + 4);   // cols 4..7
    float4 ec = *(const float4*)(er + 8);   // cols 8..11
    float4 ed = *(const float4*)(er + 12);  // cols 12..15
    const float px = ea.y, py = ea.z, vx = ea.w, vy = eb.x;
    const float speed = sqrtf(vx * vx + vy * vy);

    // all 8 neighbor rows, cols 0..4 (id, x, y, vx | vy)
    const float* nb = nei + (size_t)n * 128;
    float4 na[8]; float nvy[8];
#pragma unroll
    for (int k = 0; k < 8; ++k) {
        na[k]  = *(const float4*)(nb + k * 16);
        nvy[k] = nb[k * 16 + 4];
    }

    // recording buffer: 8 x (id, ct)
    const float* rr = rec + (size_t)n * 16;
    float bid[8], bct[8];
#pragma unroll
    for (int q = 0; q < 4; ++q) {
        float4 t = *(const float4*)(rr + q * 4);
        bid[2*q]   = t.x; bct[2*q]   = t.y;
        bid[2*q+1] = t.z; bct[2*q+1] = t.w;
    }

    // ifin mask in k-order: bid[k] present among this agent's nei ids
    unsigned finM = 0;
#pragma unroll
    for (int k = 0; k < 8; ++k) {
        bool fin = false;
#pragma unroll
        for (int j = 0; j < 8; ++j) fin = fin || (bid[k] == na[j].x);
        finM |= (fin ? 1u : 0u) << k;
    }
    const int popcFin = __popc(finM);

    // count for slot k of the argsort-select:
    //   first popcFin slots take (bct[j-th set bit]+1) in j order; rest 1.0.
    // All indexing static (full unroll + cndmask chain) — no scratch.
    float cnt[8];
#pragma unroll
    for (int k = 0; k < 8; ++k) {
        int jsel = 0, cbits = 0;
#pragma unroll
        for (int j = 0; j < 8; ++j) {
            int bit = (finM >> j) & 1;
            if (bit && cbits == k) jsel = j;
            cbits += bit;
        }
        float bj = bct[0];
#pragma unroll
        for (int j = 1; j < 8; ++j) bj = (jsel == j) ? bct[j] : bj;
        cnt[k] = (k < popcFin) ? (bj + 1.0f) : 1.0f;
    }

    // per-neighbor forces; pair-tree accumulation matches old butterfly order
    float sx[4] = {0.f, 0.f, 0.f, 0.f}, sy[4] = {0.f, 0.f, 0.f, 0.f};
#pragma unroll
    for (int k = 0; k < 8; ++k) {
        const float nid = na[k].x;
        bool match = (nid == eb.w) || (nid == ec.x) || (nid == ec.y) || (nid == ec.z)
                  || (nid == ec.w) || (nid == ed.x) || (nid == ed.y) || (nid == ed.z);
        const bool idxk = match && (nid != 0.0f);

        float rx = idxk ? (na[k].y - px) : 0.0f;
        float ry = idxk ? (na[k].z - py) : 0.0f;
        float rn = sqrtf(rx * rx + ry * ry);
        float rns = idxk ? rn : 1.0f;
        float dx = rx / rns, dy = ry / rns;

        // attraction = mono_del(count) * mono_att(rn) * dir
        float att = mono_fast(rn,     att_w1, att_b1, att_w2, att_b2);
        float del = mono_fast(cnt[k], del_w1, del_b1, del_w2, del_b2);
        float sa = del * att;
        float fax = idxk ? sa * dx : 0.0f;
        float fay = idxk ? sa * dy : 0.0f;

        float cxk = 0.0f, cyk = 0.0f;
        {
            float num = vx * fax + vy * fay;
            float fn = sqrtf(fax * fax + fay * fay);
            float den = fmaxf(speed * fn, 1e-8f);
            if (fabsf(num / den) > ang) { cxk += fax; cyk += fay; }
        }

        // repulsion
        float sxv = na[k].w * 0.02f, syv = nvy[k] * 0.02f;
        float ox = rx + sxv, oy = ry + syv;
        float bsum = rn + (ox * ox + oy * oy) - (sxv * sxv + syv * syv);
        float bgate = idxk ? bsum : 1.0f;
        float bb = sqrtf(fmaxf(bgate, 1e-12f)) * 0.5f;
        float rep = mono_fast(bb, rep_w1, rep_b1, rep_w2, rep_b2);
        float frx = idxk ? rep * dx : 0.0f;
        float fry = idxk ? rep * dy : 0.0f;
        {
            float num = vx * frx + vy * fry;
            float fn = sqrtf(frx * frx + fry * fry);
            float den = fmaxf(speed * fn, 1e-8f);
            if (fabsf(num / den) > ang) { cxk += frx; cyk += fry; }
        }

        sx[k >> 1] += cxk;   // k>>1 compile-time under full unroll
        sy[k >> 1] += cyk;
    }
    const float nbx = (sx[0] + sx[1]) + (sx[2] + sx[3]);
    const float nby = (sy[0] + sy[1]) + (sy[2] + sy[3]);

    // border force (y-only): k=0 -> border[0], k=1 -> border[3]; others zero
    float bory;
    {
        float b0v = border[0], b3v = border[3];

        float rb0 = py - b0v, rbn0 = fabsf(rb0);
        float mb0 = mono_fast(rbn0, bor_w1, bor_b1, bor_w2, bor_b2);
        float fby0 = mb0 * (rb0 / rbn0);
        float g0 = 0.0f;
        {
            float num = vy * fby0;
            float den = fmaxf(speed * fabsf(fby0), 1e-8f);
            if (fabsf(num / den) > ang) g0 = fby0;
        }

        float rb1 = py - b3v, rbn1 = fabsf(rb1);
        float mb1 = mono_fast(rbn1, bor_w1, bor_b1, bor_w2, bor_b2);
        float fby1 = mb1 * (rb1 / rbn1);
        float g1 = 0.0f;
        {
            float num = vy * fby1;
            float den = fmaxf(speed * fabsf(fby1), 1e-8f);
            if (fabsf(num / den) > ang) g1 = fby1;
        }
        bory = g0 + g1;   // butterfly added zeros for k>=2: value identical
    }

    // destination force
    float fdx = (p1 * speed - vx) / p0;
    float fdy = (0.0f - vy) / p0;
    float fdex = 0.0f, fdey = 0.0f;
    {
        float num = vx * fdx + vy * fdy;
        float fn = sqrtf(fdx * fdx + fdy * fdy);
        float den = fmaxf(speed * fn, 1e-8f);
        if (fabsf(num / den) > ang) { fdex = fdx; fdey = fdy; }
    }

    // output (N,3,2): three 8B stores, 24B/agent (8B-aligned)
    float2* o = (float2*)(out + (size_t)n * 6);
    o[0] = make_float2(fdex, fdey);
    o[1] = make_float2(nbx, nby);
    o[2] = make_float2(0.0f, bory);
}

extern "C" void kernel_launch(void* const* d_in, const int* in_sizes, int n_in,
                              void* d_out, int out_size, void* d_ws, size_t ws_size,
                              hipStream_t stream) {
    const float* ego    = (const float*)d_in[0];
    const float* nei    = (const float*)d_in[1];
    const float* border = (const float*)d_in[2];
    const float* rec    = (const float*)d_in[3];
    const float* p_dest = (const float*)d_in[4];
    const float* angle  = (const float*)d_in[5];
    const float* rep_w1 = (const float*)d_in[6];
    const float* rep_b1 = (const float*)d_in[7];
    const float* rep_w2 = (const float*)d_in[8];
    const float* rep_b2 = (const float*)d_in[9];
    const float* att_w1 = (const float*)d_in[10];
    const float* att_b1 = (const float*)d_in[11];
    const float* att_w2 = (const float*)d_in[12];
    const float* att_b2 = (const float*)d_in[13];
    const float* bor_w1 = (const float*)d_in[14];
    const float* bor_b1 = (const float*)d_in[15];
    const float* bor_w2 = (const float*)d_in[16];
    const float* bor_b2 = (const float*)d_in[17];
    const float* del_w1 = (const float*)d_in[18];
    const float* del_b1 = (const float*)d_in[19];
    const float* del_w2 = (const float*)d_in[20];
    const float* del_b2 = (const float*)d_in[21];
    float* out = (float*)d_out;

    int N = in_sizes[0] / 16;
    dim3 grid((unsigned)((N + 255) / 256));
    sfm_kernel<<<grid, 256, 0, stream>>>(
        ego, nei, border, rec, p_dest, angle,
        rep_w1, rep_b1, rep_w2, rep_b2,
        att_w1, att_b1, att_w2, att_b2,
        bor_w1, bor_b1, bor_w2, bor_b2,
        del_w1, del_b1, del_w2, del_b2,
        out, N);
}

// Round 2
// 254.301 us; speedup vs baseline: 1.0717x; 1.0717x over previous
//
#include <hip/hip_runtime.h>
#include <math.h>

#define EN 16

// mono(x) = exp(-(x*w1 + b1)) . w2 + b2  — fast native exp.
// Gate-safety: angle gates depend only on force *direction*, never on mono
// magnitudes, so __expf's ~1ulp deviation cannot flip a gate.
__device__ __forceinline__ float mono_fast(float x,
    const float* __restrict__ w1, const float* __restrict__ b1,
    const float* __restrict__ w2, const float* __restrict__ b2) {
    float acc = 0.0f;
#pragma unroll
    for (int e = 0; e < EN; ++e) {
        float pre = fmaf(x, w1[e], b1[e]);
        acc = fmaf(__expf(-pre), w2[e], acc);
    }
    return acc + b2[0];
}

// Per-(n,k) force contribution — arithmetic bit-identical to the verified
// 1-thread/agent version (same divides, same gate expressions).
__device__ __forceinline__ void do_neighbor(
    float4 na, float nvy, float cntk,
    float px, float py, float vx, float vy, float speed, float ang,
    float m0, float m1, float m2, float m3,
    float m4, float m5, float m6, float m7,
    const float* __restrict__ rep_w1, const float* __restrict__ rep_b1,
    const float* __restrict__ rep_w2, const float* __restrict__ rep_b2,
    const float* __restrict__ att_w1, const float* __restrict__ att_b1,
    const float* __restrict__ att_w2, const float* __restrict__ att_b2,
    const float* __restrict__ del_w1, const float* __restrict__ del_b1,
    const float* __restrict__ del_w2, const float* __restrict__ del_b2,
    float& cxk, float& cyk)
{
    const float nid = na.x;
    bool match = (nid == m0) || (nid == m1) || (nid == m2) || (nid == m3)
              || (nid == m4) || (nid == m5) || (nid == m6) || (nid == m7);
    const bool idxk = match && (nid != 0.0f);

    float rx = idxk ? (na.y - px) : 0.0f;
    float ry = idxk ? (na.z - py) : 0.0f;
    float rn = sqrtf(rx * rx + ry * ry);
    float rns = idxk ? rn : 1.0f;
    float dx = rx / rns, dy = ry / rns;

    // attraction = mono_del(count) * mono_att(rn) * dir
    float att = mono_fast(rn,   att_w1, att_b1, att_w2, att_b2);
    float del = mono_fast(cntk, del_w1, del_b1, del_w2, del_b2);
    float sa = del * att;
    float fax = idxk ? sa * dx : 0.0f;
    float fay = idxk ? sa * dy : 0.0f;

    cxk = 0.0f; cyk = 0.0f;
    {
        float num = vx * fax + vy * fay;
        float fn = sqrtf(fax * fax + fay * fay);
        float den = fmaxf(speed * fn, 1e-8f);
        if (fabsf(num / den) > ang) { cxk += fax; cyk += fay; }
    }

    // repulsion
    float sxv = na.w * 0.02f, syv = nvy * 0.02f;
    float ox = rx + sxv, oy = ry + syv;
    float bsum = rn + (ox * ox + oy * oy) - (sxv * sxv + syv * syv);
    float bgate = idxk ? bsum : 1.0f;
    float bb = sqrtf(fmaxf(bgate, 1e-12f)) * 0.5f;
    float rep = mono_fast(bb, rep_w1, rep_b1, rep_w2, rep_b2);
    float frx = idxk ? rep * dx : 0.0f;
    float fry = idxk ? rep * dy : 0.0f;
    {
        float num = vx * frx + vy * fry;
        float fn = sqrtf(frx * frx + fry * fry);
        float den = fmaxf(speed * fn, 1e-8f);
        if (fabsf(num / den) > ang) { cxk += frx; cyk += fry; }
    }
}

// 4 lanes per agent, 2 neighbors per lane.
// vs 1-thread/agent (85us, occ 19%): 4x the waves (16384 -> 4x block
// replacement over the 4-wave/SIMD residency cap), 1/4 the serial chain.
// vs the original 8-lane version: half the shuffles, fewer redundant monos.
// Reduction association reproduces ((p0+p1)+(p2+p3)) with p_s = cx(2s)+cx(2s+1),
// identical to both prior verified kernels.
extern "C" __global__ void __launch_bounds__(256)
sfm_kernel(const float* __restrict__ ego, const float* __restrict__ nei,
           const float* __restrict__ border, const float* __restrict__ rec,
           const float* __restrict__ p_dest, const float* __restrict__ angle,
           const float* __restrict__ rep_w1, const float* __restrict__ rep_b1,
           const float* __restrict__ rep_w2, const float* __restrict__ rep_b2,
           const float* __restrict__ att_w1, const float* __restrict__ att_b1,
           const float* __restrict__ att_w2, const float* __restrict__ att_b2,
           const float* __restrict__ bor_w1, const float* __restrict__ bor_b1,
           const float* __restrict__ bor_w2, const float* __restrict__ bor_b2,
           const float* __restrict__ del_w1, const float* __restrict__ del_b1,
           const float* __restrict__ del_w2, const float* __restrict__ del_b2,
           float* __restrict__ out, int N)
{
    const int gid = blockIdx.x * blockDim.x + threadIdx.x;
    const int n = gid >> 2;      // agent
    const int s = gid & 3;       // sub-lane: neighbors 2s, 2s+1
    if (n >= N) return;
    const int lane = threadIdx.x & 63;
    const int gbase = lane & ~3; // first lane of this agent's 4-lane group

    const float ang = angle[0];
    const float p0 = p_dest[0], p1 = p_dest[1];

    // ego row (same 64B line for all 4 lanes -> L1 broadcast)
    const float* er = ego + (size_t)n * 16;
    float4 ea = *(const float4*)(er);       // cols 0..3
    float4 eb = *(const float4*)(er + 4);   // cols 4..7
    float4 ec = *(const float4*)(er + 8);   // cols 8..11
    float4 ed = *(const float4*)(er + 12);  // cols 12..15
    const float px = ea.y, py = ea.z, vx = ea.w, vy = eb.x;
    const float speed = sqrtf(vx * vx + vy * vy);
    const float m0 = eb.w, m1 = ec.x, m2 = ec.y, m3 = ec.z;
    const float m4 = ec.w, m5 = ed.x, m6 = ed.y, m7 = ed.z;

    // my two neighbor rows (cols 0..4)
    const int k0 = 2 * s, k1 = 2 * s + 1;
    const float* nb = nei + (size_t)n * 128;
    float4 na0 = *(const float4*)(nb + k0 * 16);
    float  nv0 = nb[k0 * 16 + 4];
    float4 na1 = *(const float4*)(nb + k1 * 16);
    float  nv1 = nb[k1 * 16 + 4];

    // my two recording slots (2s, 2s+1): perfectly coalesced 16B/lane
    float4 rcv = *(const float4*)(rec + (size_t)n * 16 + s * 4);
    const float bidA = rcv.x, bctA = rcv.y;
    const float bidB = rcv.z, bctB = rcv.w;

    // gather all 8 nei ids of this agent (3 xor-shuffles per held id)
    const float g0 = na0.x, g1 = na1.x;
    const float x1a = __shfl_xor(g0, 1), x1b = __shfl_xor(g1, 1);
    const float x2a = __shfl_xor(g0, 2), x2b = __shfl_xor(g1, 2);
    const float x3a = __shfl_xor(g0, 3), x3b = __shfl_xor(g1, 3);

    // ifin for my two buffer slots: bid present among the 8 nei ids
    bool finA = (bidA == g0) || (bidA == g1) || (bidA == x1a) || (bidA == x1b)
             || (bidA == x2a) || (bidA == x2b) || (bidA == x3a) || (bidA == x3b);
    bool finB = (bidB == g0) || (bidB == g1) || (bidB == x1a) || (bidB == x1b)
             || (bidB == x2a) || (bidB == x2b) || (bidB == x3a) || (bidB == x3b);

    unsigned long long balA = __ballot(finA);
    unsigned long long balB = __ballot(finB);
    unsigned mA = (unsigned)((balA >> gbase) & 0xFull); // bit l = fin[2l]
    unsigned mB = (unsigned)((balB >> gbase) & 0xFull); // bit l = fin[2l+1]
    unsigned finM = 0;
#pragma unroll
    for (int l = 0; l < 4; ++l)
        finM |= (((mA >> l) & 1u) << (2 * l)) | (((mB >> l) & 1u) << (2 * l + 1));
    const int popcFin = __popc(finM);

    // count for my slots k0,k1 of the argsort-select:
    //   first popcFin slots take (bct[j-th set bit]+1) in j order; rest 1.0.
    // No runtime-indexed arrays: cndmask chain + dynamic __shfl (bpermute).
    float cntv[2];
#pragma unroll
    for (int t = 0; t < 2; ++t) {
        const int k = 2 * s + t;
        int jsel = 0, cbits = 0;
#pragma unroll
        for (int j = 0; j < 8; ++j) {
            int bit = (finM >> j) & 1;
            if (bit && cbits == k) jsel = j;
            cbits += bit;
        }
        int owner = gbase + (jsel >> 1);         // lane holding slot jsel
        float lo = __shfl(bctA, owner);          // bct[2*(jsel>>1)]
        float hi = __shfl(bctB, owner);          // bct[2*(jsel>>1)+1]
        float bj = (jsel & 1) ? hi : lo;         // bct[jsel]
        cntv[t] = (k < popcFin) ? (bj + 1.0f) : 1.0f;
    }

    // my two neighbors; pair sum p_s = cx(2s) + cx(2s+1)
    float cx0, cy0, cx1, cy1;
    do_neighbor(na0, nv0, cntv[0], px, py, vx, vy, speed, ang,
                m0, m1, m2, m3, m4, m5, m6, m7,
                rep_w1, rep_b1, rep_w2, rep_b2,
                att_w1, att_b1, att_w2, att_b2,
                del_w1, del_b1, del_w2, del_b2, cx0, cy0);
    do_neighbor(na1, nv1, cntv[1], px, py, vx, vy, speed, ang,
                m0, m1, m2, m3, m4, m5, m6, m7,
                rep_w1, rep_b1, rep_w2, rep_b2,
                att_w1, att_b1, att_w2, att_b2,
                del_w1, del_b1, del_w2, del_b2, cx1, cy1);
    float pxs = cx0 + cx1;
    float pys = cy0 + cy1;

    // border force (y-only): slot s=0 -> border[0], s=1 -> border[3];
    // s=2,3 compute a dummy (uniform instruction stream) gated to zero.
    float gb = 0.0f;
    {
        float bsel = (s == 1) ? border[3] : border[0];
        float rb = py - bsel;
        float rbn = fabsf(rb);
        float mb = mono_fast(rbn, bor_w1, bor_b1, bor_w2, bor_b2);
        float fby = mb * (rb / rbn);
        float num = vy * fby;
        float den = fmaxf(speed * fabsf(fby), 1e-8f);
        if ((fabsf(num / den) > ang) && (s < 2)) gb = fby;
    }

    // xor-butterfly over the 4-lane group: ((p0+p1)+(p2+p3)) — identical
    // association to the verified kernels; border gets (g0+g1)+(0+0)=g0+g1.
    pxs += __shfl_xor(pxs, 1);  pys += __shfl_xor(pys, 1);  gb += __shfl_xor(gb, 1);
    pxs += __shfl_xor(pxs, 2);  pys += __shfl_xor(pys, 2);  gb += __shfl_xor(gb, 2);

    // destination force (uniform, cheap: compute everywhere)
    float fdx = (p1 * speed - vx) / p0;
    float fdy = (0.0f - vy) / p0;
    float fdex = 0.0f, fdey = 0.0f;
    {
        float num = vx * fdx + vy * fdy;
        float fn = sqrtf(fdx * fdx + fdy * fdy);
        float den = fmaxf(speed * fn, 1e-8f);
        if (fabsf(num / den) > ang) { fdex = fdx; fdey = fdy; }
    }

    // output (N,3,2): lanes s=0,1,2 each store one float2 (24B/agent contiguous)
    float2 wv = (s == 0) ? make_float2(fdex, fdey)
              : (s == 1) ? make_float2(pxs, pys)
              :            make_float2(0.0f, gb);
    if (s < 3) *(float2*)(out + (size_t)n * 6 + 2 * s) = wv;
}

extern "C" void kernel_launch(void* const* d_in, const int* in_sizes, int n_in,
                              void* d_out, int out_size, void* d_ws, size_t ws_size,
                              hipStream_t stream) {
    const float* ego    = (const float*)d_in[0];
    const float* nei    = (const float*)d_in[1];
    const float* border = (const float*)d_in[2];
    const float* rec    = (const float*)d_in[3];
    const float* p_dest = (const float*)d_in[4];
    const float* angle  = (const float*)d_in[5];
    const float* rep_w1 = (const float*)d_in[6];
    const float* rep_b1 = (const float*)d_in[7];
    const float* rep_w2 = (const float*)d_in[8];
    const float* rep_b2 = (const float*)d_in[9];
    const float* att_w1 = (const float*)d_in[10];
    const float* att_b1 = (const float*)d_in[11];
    const float* att_w2 = (const float*)d_in[12];
    const float* att_b2 = (const float*)d_in[13];
    const float* bor_w1 = (const float*)d_in[14];
    const float* bor_b1 = (const float*)d_in[15];
    const float* bor_w2 = (const float*)d_in[16];
    const float* bor_b2 = (const float*)d_in[17];
    const float* del_w1 = (const float*)d_in[18];
    const float* del_b1 = (const float*)d_in[19];
    const float* del_w2 = (const float*)d_in[20];
    const float* del_b2 = (const float*)d_in[21];
    float* out = (float*)d_out;

    int N = in_sizes[0] / 16;
    long long threads = (long long)N * 4;
    dim3 grid((unsigned)((threads + 255) / 256));
    sfm_kernel<<<grid, 256, 0, stream>>>(
        ego, nei, border, rec, p_dest, angle,
        rep_w1, rep_b1, rep_w2, rep_b2,
        att_w1, att_b1, att_w2, att_b2,
        bor_w1, bor_b1, bor_w2, bor_b2,
        del_w1, del_b1, del_w2, del_b2,
        out, N);
}